// Round 1
// baseline (906.888 us; speedup 1.0000x reference)
//
#include <hip/hip_runtime.h>
#include <stdint.h>

#define B_ROWS 4096
#define D_DIM  1024
#define E_NUM  8
#define C_DIM  4096
#define LOSS_COEF 0.01f
#define EPS_COMBINE 2.220446049250313e-16f

typedef float  f32x4  __attribute__((ext_vector_type(4)));
typedef __bf16 bf16x8 __attribute__((ext_vector_type(8)));

// RNE float -> bf16 bits (values here are tame; no NaN handling needed)
static __device__ __forceinline__ unsigned short f2bf(float f) {
    unsigned int u = __float_as_uint(f);
    u += 0x7fffu + ((u >> 16) & 1u);
    return (unsigned short)(u >> 16);
}

// async global->LDS, 16B per lane; LDS dest = wave-uniform base + lane*16
static __device__ __forceinline__ void async16(const void* g, void* l) {
    __builtin_amdgcn_global_load_lds(
        (const __attribute__((address_space(1))) unsigned int*)g,
        (__attribute__((address_space(3))) unsigned int*)l, 16, 0, 0);
}

__global__ void zero_stats_kernel(float* __restrict__ stats) {
    if (threadIdx.x < 16) stats[threadIdx.x] = 0.0f;
}

__global__ void cvt_x_kernel(const float4* __restrict__ xin, unsigned short* __restrict__ xb) {
    int i = blockIdx.x * blockDim.x + threadIdx.x;   // 1M threads, 4 elems each
    float4 v = xin[i];
    unsigned short h[4] = { f2bf(v.x), f2bf(v.y), f2bf(v.z), f2bf(v.w) };
    *(uint2*)(xb + (size_t)i * 4) = *(const uint2*)h;
}

// logits = x @ w_gate; top-4 softmax -> gates[4096][8]; importance/load atomics
__global__ void gating_kernel(const float* __restrict__ x,
                              const float* __restrict__ wg,
                              float* __restrict__ gates,
                              float* __restrict__ stats) {
    __shared__ float simp[E_NUM], sload[E_NUM];
    const int tid = threadIdx.x;
    if (tid < E_NUM) { simp[tid] = 0.0f; sload[tid] = 0.0f; }
    __syncthreads();
    const int lane = tid & 63;
    const int wid  = tid >> 6;
    for (int i = 0; i < 16; ++i) {
        int row = blockIdx.x * 64 + wid * 16 + i;
        float acc[8] = {0.f,0.f,0.f,0.f,0.f,0.f,0.f,0.f};
        for (int d = lane; d < D_DIM; d += 64) {
            float xv = x[(size_t)row * D_DIM + d];
            const float4* wp = (const float4*)(wg + d * 8);
            float4 w0 = wp[0], w1 = wp[1];
            acc[0] += xv * w0.x; acc[1] += xv * w0.y;
            acc[2] += xv * w0.z; acc[3] += xv * w0.w;
            acc[4] += xv * w1.x; acc[5] += xv * w1.y;
            acc[6] += xv * w1.z; acc[7] += xv * w1.w;
        }
        #pragma unroll
        for (int off = 32; off > 0; off >>= 1)
            #pragma unroll
            for (int e = 0; e < 8; ++e)
                acc[e] += __shfl_xor(acc[e], off, 64);
        if (lane == 0) {
            float val[4]; int idx[4]; unsigned used = 0;
            #pragma unroll
            for (int j = 0; j < 4; ++j) {               // strict > : lowest index wins ties (lax.top_k)
                float best = -1e30f; int bi = 0;
                for (int ee = 0; ee < 8; ++ee)
                    if (!(used & (1u << ee)) && acc[ee] > best) { best = acc[ee]; bi = ee; }
                used |= 1u << bi; val[j] = best; idx[j] = bi;
            }
            float mx = val[0], sum = 0.f, gv[4];
            #pragma unroll
            for (int j = 0; j < 4; ++j) { gv[j] = __expf(val[j] - mx); sum += gv[j]; }
            float inv = 1.0f / sum;
            float gout[8] = {0.f,0.f,0.f,0.f,0.f,0.f,0.f,0.f};
            #pragma unroll
            for (int j = 0; j < 4; ++j) gout[idx[j]] = gv[j] * inv;
            #pragma unroll
            for (int e = 0; e < 8; ++e) gates[(size_t)row * 8 + e] = gout[e];
            #pragma unroll
            for (int j = 0; j < 4; ++j) {
                atomicAdd(&simp[idx[j]], gv[j] * inv);
                atomicAdd(&sload[idx[j]], 1.0f);
            }
        }
    }
    __syncthreads();
    if (tid < E_NUM) {
        atomicAdd(&stats[tid],          simp[tid]);
        atomicAdd(&stats[E_NUM + tid],  sload[tid]);
    }
}

__global__ void loss_kernel(const float* __restrict__ stats, float* __restrict__ out_loss) {
    if (threadIdx.x == 0) {
        float mi = 0.f, ml = 0.f;
        for (int e = 0; e < 8; ++e) { mi += stats[e]; ml += stats[8 + e]; }
        mi *= 0.125f; ml *= 0.125f;
        float vi = 0.f, vl = 0.f;
        for (int e = 0; e < 8; ++e) {
            float a = stats[e] - mi;     vi += a * a;
            float b = stats[8 + e] - ml; vl += b * b;
        }
        vi *= (1.0f / 7.0f); vl *= (1.0f / 7.0f);
        out_loss[0] = (vi / (mi * mi + 1e-10f) + vl / (ml * ml + 1e-10f)) * LOSS_COEF;
    }
}

// Fused dense MoE: per 128x128 tile, for each expert: bf16 MFMA GEMM over K=1024,
// then comb += gate * exp(acc + bias); final y = log(comb).
__global__ __launch_bounds__(256, 2) void moe_main_kernel(
    const unsigned short* __restrict__ xb,   // bf16 bits [4096][1024]
    const float* __restrict__ wexp,          // [8][1024][4096] fp32
    const float* __restrict__ bexp,          // [8][4096]
    const float* __restrict__ gates,         // [4096][8]
    float* __restrict__ out)                 // [4096][4096] (+ loss elsewhere)
{
    __shared__ unsigned short As[128 * 32];  // [m][k], k contiguous (64B rows), 8KB
    __shared__ unsigned short Bs[128 * 40];  // [n][k], stride 40 (pad), 10KB
    __shared__ float gs[128 * 8];            // gates tile
    __shared__ float bs[8 * 128];            // bias tile

    const int tid  = threadIdx.x;
    const int lane = tid & 63;
    const int wid  = tid >> 6;
    const int wm   = wid >> 1;     // 2x2 wave grid, each wave 64x64
    const int wn   = wid & 1;
    const int q    = lane >> 4;    // quad
    const int ln   = lane & 15;
    const int row0 = blockIdx.x * 128;
    const int col0 = blockIdx.y * 128;

    // stage gates + bias tiles (ordered by first __syncthreads in K loop)
    ((float4*)gs)[tid] = ((const float4*)(gates + (size_t)row0 * 8))[tid];
    {
        int e = tid >> 5, c4 = (tid & 31) * 4;
        *(float4*)(bs + e * 128 + c4) = *(const float4*)(bexp + (size_t)e * C_DIM + col0 + c4);
    }

    const f32x4 vzero = {0.f, 0.f, 0.f, 0.f};
    f32x4 comb[4][4];
    #pragma unroll
    for (int i = 0; i < 4; ++i)
        #pragma unroll
        for (int j = 0; j < 4; ++j) comb[i][j] = vzero;

    // A staging: thread -> (row tid>>2, k8 (tid&3)*8); two 4KB halves per k-tile
    const int mA = tid >> 2;
    const int kA = (tid & 3) * 8;
    const unsigned short* gA = xb + (size_t)(row0 + mA) * D_DIM + kA;
    char* ldsA = (char*)As + wid * 1024;     // wave-uniform base; HW adds lane*16

    // B staging: thread -> column n (tid&127), k half (tid>>7)*16 .. +15
    const int nB  = tid & 127;
    const int khB = tid >> 7;

    for (int e = 0; e < E_NUM; ++e) {
        f32x4 acc[4][4];
        #pragma unroll
        for (int i = 0; i < 4; ++i)
            #pragma unroll
            for (int j = 0; j < 4; ++j) acc[i][j] = vzero;

        const float* wE = wexp + (size_t)e * D_DIM * C_DIM + col0 + nB;
        const float* gB = wE + (size_t)khB * 16 * C_DIM;

        for (int kt = 0; kt < D_DIM / 32; ++kt) {
            // A: async bf16 global->LDS (rows 0-63, then 64-127)
            const unsigned short* ga = gA + kt * 32;
            async16(ga,               ldsA);
            async16(ga + 64 * D_DIM,  ldsA + 4096);

            // B: 16 coalesced fp32 loads (fixed n, k-consecutive), cvt, transpose-store
            float bv[16];
            const float* gw = gB + (size_t)kt * 32 * C_DIM;
            #pragma unroll
            for (int i = 0; i < 16; ++i) bv[i] = gw[(size_t)i * C_DIM];
            unsigned short bh[16];
            #pragma unroll
            for (int i = 0; i < 16; ++i) bh[i] = f2bf(bv[i]);
            *(uint4*)(Bs + nB * 40 + khB * 16)     = ((const uint4*)bh)[0];
            *(uint4*)(Bs + nB * 40 + khB * 16 + 8) = ((const uint4*)bh)[1];

            __syncthreads();

            bf16x8 af[4], bfr[4];
            #pragma unroll
            for (int fm = 0; fm < 4; ++fm)
                af[fm] = *(const bf16x8*)(As + (wm * 64 + fm * 16 + ln) * 32 + q * 8);
            #pragma unroll
            for (int fn = 0; fn < 4; ++fn)
                bfr[fn] = *(const bf16x8*)(Bs + (wn * 64 + fn * 16 + ln) * 40 + q * 8);
            #pragma unroll
            for (int fm = 0; fm < 4; ++fm)
                #pragma unroll
                for (int fn = 0; fn < 4; ++fn)
                    acc[fm][fn] = __builtin_amdgcn_mfma_f32_16x16x32_bf16(
                        af[fm], bfr[fn], acc[fm][fn], 0, 0, 0);

            __syncthreads();
        }

        // epilogue: comb += gate * exp(acc + bias)   (C/D: col=ln, row=q*4+r)
        #pragma unroll
        for (int fn = 0; fn < 4; ++fn) {
            float bval = bs[e * 128 + wn * 64 + fn * 16 + ln];
            #pragma unroll
            for (int fm = 0; fm < 4; ++fm)
                #pragma unroll
                for (int r = 0; r < 4; ++r) {
                    float g = gs[(wm * 64 + fm * 16 + q * 4 + r) * 8 + e];
                    comb[fm][fn][r] += g * __expf(acc[fm][fn][r] + bval);
                }
        }
    }

    #pragma unroll
    for (int fm = 0; fm < 4; ++fm)
        #pragma unroll
        for (int fn = 0; fn < 4; ++fn)
            #pragma unroll
            for (int r = 0; r < 4; ++r) {
                int row = row0 + wm * 64 + fm * 16 + q * 4 + r;
                int col = col0 + wn * 64 + fn * 16 + ln;
                float c = comb[fm][fn][r];
                c = (c == 0.0f) ? EPS_COMBINE : c;
                out[(size_t)row * C_DIM + col] = __logf(c);
            }
}

extern "C" void kernel_launch(void* const* d_in, const int* in_sizes, int n_in,
                              void* d_out, int out_size, void* d_ws, size_t ws_size,
                              hipStream_t stream) {
    const float* x    = (const float*)d_in[0];
    const float* wg   = (const float*)d_in[1];
    const float* wexp = (const float*)d_in[2];
    const float* bexp = (const float*)d_in[3];
    // d_in[4] is k==4 (hard-coded in kernels)
    float* out = (float*)d_out;
    char*  ws  = (char*)d_ws;

    unsigned short* xb    = (unsigned short*)ws;           // 8388608 B
    float*          gates = (float*)(ws + 8388608);        // 131072 B
    float*          stats = (float*)(ws + 8519680);        // 64 B

    zero_stats_kernel<<<1, 64, 0, stream>>>(stats);
    cvt_x_kernel<<<(B_ROWS * D_DIM / 4) / 256, 256, 0, stream>>>((const float4*)x, xb);
    gating_kernel<<<B_ROWS / 64, 256, 0, stream>>>(x, wg, gates, stats);
    loss_kernel<<<1, 64, 0, stream>>>(stats, out + (size_t)B_ROWS * C_DIM);

    dim3 grid(B_ROWS / 128, C_DIM / 128);
    moe_main_kernel<<<grid, 256, 0, stream>>>(xb, wexp, bexp, gates, out);
}

// Round 2
// 677.933 us; speedup vs baseline: 1.3377x; 1.3377x over previous
//
#include <hip/hip_runtime.h>
#include <stdint.h>

#define B_ROWS 4096
#define D_DIM  1024
#define E_NUM  8
#define C_DIM  4096
#define LOSS_COEF 0.01f
#define EPS_COMBINE 2.220446049250313e-16f

typedef float  f32x4  __attribute__((ext_vector_type(4)));
typedef __bf16 bf16x8 __attribute__((ext_vector_type(8)));

// RNE float -> bf16 bits (values here are tame; no NaN handling needed)
static __device__ __forceinline__ unsigned short f2bf(float f) {
    unsigned int u = __float_as_uint(f);
    u += 0x7fffu + ((u >> 16) & 1u);
    return (unsigned short)(u >> 16);
}

// async global->LDS, 16B per lane; LDS dest = wave-uniform base + lane*16
static __device__ __forceinline__ void async16(const void* g, void* l) {
    __builtin_amdgcn_global_load_lds(
        (const __attribute__((address_space(1))) unsigned int*)g,
        (__attribute__((address_space(3))) unsigned int*)l, 16, 0, 0);
}

__global__ void zero_stats_kernel(float* __restrict__ stats) {
    if (threadIdx.x < 16) stats[threadIdx.x] = 0.0f;
}

__global__ void cvt_x_kernel(const float4* __restrict__ xin, unsigned short* __restrict__ xb) {
    int i = blockIdx.x * blockDim.x + threadIdx.x;   // 1M threads, 4 elems each
    float4 v = xin[i];
    unsigned short h[4] = { f2bf(v.x), f2bf(v.y), f2bf(v.z), f2bf(v.w) };
    *(uint2*)(xb + (size_t)i * 4) = *(const uint2*)h;
}

// w_exp [8][1024][4096] fp32  ->  wT [8][4096][1024] bf16 (k-contiguous)
__global__ __launch_bounds__(256) void transpose_wexp_kernel(
    const float* __restrict__ wexp, unsigned short* __restrict__ wT) {
    __shared__ float T[64][65];          // +1 pad breaks bank conflicts
    const int e  = blockIdx.z;
    const int k0 = blockIdx.y * 64;
    const int c0 = blockIdx.x * 64;
    const int t  = threadIdx.x;
    const int cc = t & 63;
    const int kb = t >> 6;               // 0..3
    const float* src = wexp + ((size_t)e * D_DIM + k0) * C_DIM + c0;
    #pragma unroll
    for (int i = 0; i < 16; ++i) {
        int kr = i * 4 + kb;
        T[kr][cc] = src[(size_t)kr * C_DIM + cc];   // coalesced 64-float rows
    }
    __syncthreads();
    #pragma unroll
    for (int j = 0; j < 2; ++j) {
        int chunk = j * 256 + t;
        int cl = chunk >> 3;             // local c
        int k8 = (chunk & 7) * 8;        // k chunk
        unsigned short h[8];
        #pragma unroll
        for (int i = 0; i < 8; ++i) h[i] = f2bf(T[k8 + i][cl]);
        *(uint4*)(wT + ((size_t)(e * C_DIM + c0 + cl)) * D_DIM + k0 + k8) =
            *(const uint4*)h;            // coalesced 16B chunks along k
    }
}

// logits = x @ w_gate; top-4 softmax -> gates[4096][8]; importance/load atomics
__global__ void gating_kernel(const float* __restrict__ x,
                              const float* __restrict__ wg,
                              float* __restrict__ gates,
                              float* __restrict__ stats) {
    __shared__ float simp[E_NUM], sload[E_NUM];
    const int tid = threadIdx.x;
    if (tid < E_NUM) { simp[tid] = 0.0f; sload[tid] = 0.0f; }
    __syncthreads();
    const int lane = tid & 63;
    const int wid  = tid >> 6;
    for (int i = 0; i < 16; ++i) {
        int row = blockIdx.x * 64 + wid * 16 + i;
        float acc[8] = {0.f,0.f,0.f,0.f,0.f,0.f,0.f,0.f};
        for (int d = lane; d < D_DIM; d += 64) {
            float xv = x[(size_t)row * D_DIM + d];
            const float4* wp = (const float4*)(wg + d * 8);
            float4 w0 = wp[0], w1 = wp[1];
            acc[0] += xv * w0.x; acc[1] += xv * w0.y;
            acc[2] += xv * w0.z; acc[3] += xv * w0.w;
            acc[4] += xv * w1.x; acc[5] += xv * w1.y;
            acc[6] += xv * w1.z; acc[7] += xv * w1.w;
        }
        #pragma unroll
        for (int off = 32; off > 0; off >>= 1)
            #pragma unroll
            for (int e = 0; e < 8; ++e)
                acc[e] += __shfl_xor(acc[e], off, 64);
        if (lane == 0) {
            float val[4]; int idx[4]; unsigned used = 0;
            #pragma unroll
            for (int j = 0; j < 4; ++j) {               // strict > : lowest index wins ties (lax.top_k)
                float best = -1e30f; int bi = 0;
                for (int ee = 0; ee < 8; ++ee)
                    if (!(used & (1u << ee)) && acc[ee] > best) { best = acc[ee]; bi = ee; }
                used |= 1u << bi; val[j] = best; idx[j] = bi;
            }
            float mx = val[0], sum = 0.f, gv[4];
            #pragma unroll
            for (int j = 0; j < 4; ++j) { gv[j] = __expf(val[j] - mx); sum += gv[j]; }
            float inv = 1.0f / sum;
            float gout[8] = {0.f,0.f,0.f,0.f,0.f,0.f,0.f,0.f};
            #pragma unroll
            for (int j = 0; j < 4; ++j) gout[idx[j]] = gv[j] * inv;
            #pragma unroll
            for (int e = 0; e < 8; ++e) gates[(size_t)row * 8 + e] = gout[e];
            #pragma unroll
            for (int j = 0; j < 4; ++j) {
                atomicAdd(&simp[idx[j]], gv[j] * inv);
                atomicAdd(&sload[idx[j]], 1.0f);
            }
        }
    }
    __syncthreads();
    if (tid < E_NUM) {
        atomicAdd(&stats[tid],          simp[tid]);
        atomicAdd(&stats[E_NUM + tid],  sload[tid]);
    }
}

__global__ void loss_kernel(const float* __restrict__ stats, float* __restrict__ out_loss) {
    if (threadIdx.x == 0) {
        float mi = 0.f, ml = 0.f;
        for (int e = 0; e < 8; ++e) { mi += stats[e]; ml += stats[8 + e]; }
        mi *= 0.125f; ml *= 0.125f;
        float vi = 0.f, vl = 0.f;
        for (int e = 0; e < 8; ++e) {
            float a = stats[e] - mi;     vi += a * a;
            float b = stats[8 + e] - ml; vl += b * b;
        }
        vi *= (1.0f / 7.0f); vl *= (1.0f / 7.0f);
        out_loss[0] = (vi / (mi * mi + 1e-10f) + vl / (ml * ml + 1e-10f)) * LOSS_COEF;
    }
}

// Fused dense MoE: per 128x128 tile, for each expert: bf16 MFMA GEMM over K=1024,
// then comb += gate * exp(acc + bias); final y = log(comb).
// Both A and B staged via global_load_lds dwordx4 with XOR chunk swizzle:
// LDS slot (row, qs) holds global chunk qg = qs ^ (row&3); fragment read uses
// chunk q at (q ^ (ln&3)) -> each 16-lane b128 read phase covers all 8 bank
// groups (conflict-free, no padding -- padding would break async staging).
__global__ __launch_bounds__(256, 3) void moe_main_kernel(
    const unsigned short* __restrict__ xb,   // bf16 bits [4096][1024]
    const unsigned short* __restrict__ wT,   // bf16 bits [8][4096][1024]
    const float* __restrict__ bexp,          // [8][4096]
    const float* __restrict__ gates,         // [4096][8]
    float* __restrict__ out)                 // [4096][4096] (+ loss elsewhere)
{
    __shared__ unsigned short As[128 * 32];  // [m][k-chunk swizzled], 8KB
    __shared__ unsigned short Bs[128 * 32];  // [n][k-chunk swizzled], 8KB
    __shared__ float gs[128 * 8];            // gates tile, 4KB
    __shared__ float bs[8 * 128];            // bias tile,  4KB

    const int tid  = threadIdx.x;
    const int lane = tid & 63;
    const int wid  = tid >> 6;
    const int wm   = wid >> 1;     // 2x2 wave grid, each wave 64x64
    const int wn   = wid & 1;
    const int q    = lane >> 4;    // quad
    const int ln   = lane & 15;
    const int row0 = blockIdx.x * 128;
    const int col0 = blockIdx.y * 128;

    // stage gates + bias tiles (ordered by first __syncthreads in K loop)
    ((float4*)gs)[tid] = ((const float4*)(gates + (size_t)row0 * 8))[tid];
    {
        int e = tid >> 5, c4 = (tid & 31) * 4;
        *(float4*)(bs + e * 128 + c4) = *(const float4*)(bexp + (size_t)e * C_DIM + col0 + c4);
    }

    const f32x4 vzero = {0.f, 0.f, 0.f, 0.f};
    f32x4 comb[4][4];
    #pragma unroll
    for (int i = 0; i < 4; ++i)
        #pragma unroll
        for (int j = 0; j < 4; ++j) comb[i][j] = vzero;

    // staging maps: thread tid -> LDS slot (row = tid>>2, qs = tid&3);
    // source chunk qg = qs ^ (row&3)  (XOR swizzle)
    const int rS = tid >> 2;
    const int qg = (tid & 3) ^ (rS & 3);
    const unsigned short* gA = xb + (size_t)(row0 + rS) * D_DIM + qg * 8;
    const unsigned short* gBb = wT + ((size_t)(col0 + rS)) * D_DIM + qg * 8;
    char* ldsA = (char*)As + wid * 1024;     // wave-uniform base; HW adds lane*16
    char* ldsB = (char*)Bs + wid * 1024;

    const int fq = (q << 3) ^ ((ln & 3) << 3);  // swizzled fragment chunk offset (shorts)

    for (int e = 0; e < E_NUM; ++e) {
        f32x4 acc[4][4];
        #pragma unroll
        for (int i = 0; i < 4; ++i)
            #pragma unroll
            for (int j = 0; j < 4; ++j) acc[i][j] = vzero;

        const unsigned short* gB = gBb + (size_t)e * C_DIM * D_DIM;

        for (int kt = 0; kt < D_DIM / 32; ++kt) {
            const unsigned short* ga = gA + kt * 32;
            const unsigned short* gb = gB + kt * 32;
            async16(ga,                ldsA);          // rows 0-63
            async16(ga + 64 * D_DIM,   ldsA + 4096);   // rows 64-127
            async16(gb,                ldsB);          // cols 0-63
            async16(gb + 64 * D_DIM,   ldsB + 4096);   // cols 64-127

            __syncthreads();

            bf16x8 af[4], bfr[4];
            #pragma unroll
            for (int fm = 0; fm < 4; ++fm)
                af[fm] = *(const bf16x8*)(As + (wm * 64 + fm * 16 + ln) * 32 + fq);
            #pragma unroll
            for (int fn = 0; fn < 4; ++fn)
                bfr[fn] = *(const bf16x8*)(Bs + (wn * 64 + fn * 16 + ln) * 32 + fq);
            #pragma unroll
            for (int fm = 0; fm < 4; ++fm)
                #pragma unroll
                for (int fn = 0; fn < 4; ++fn)
                    acc[fm][fn] = __builtin_amdgcn_mfma_f32_16x16x32_bf16(
                        af[fm], bfr[fn], acc[fm][fn], 0, 0, 0);

            __syncthreads();
        }

        // epilogue: comb += gate * exp(acc + bias)   (C/D: col=ln, row=q*4+r)
        #pragma unroll
        for (int fn = 0; fn < 4; ++fn) {
            float bval = bs[e * 128 + wn * 64 + fn * 16 + ln];
            #pragma unroll
            for (int fm = 0; fm < 4; ++fm)
                #pragma unroll
                for (int r = 0; r < 4; ++r) {
                    float g = gs[(wm * 64 + fm * 16 + q * 4 + r) * 8 + e];
                    comb[fm][fn][r] += g * __expf(acc[fm][fn][r] + bval);
                }
        }
    }

    #pragma unroll
    for (int fm = 0; fm < 4; ++fm)
        #pragma unroll
        for (int fn = 0; fn < 4; ++fn)
            #pragma unroll
            for (int r = 0; r < 4; ++r) {
                int row = row0 + wm * 64 + fm * 16 + q * 4 + r;
                int col = col0 + wn * 64 + fn * 16 + ln;
                float c = comb[fm][fn][r];
                c = (c == 0.0f) ? EPS_COMBINE : c;
                out[(size_t)row * C_DIM + col] = __logf(c);
            }
}

extern "C" void kernel_launch(void* const* d_in, const int* in_sizes, int n_in,
                              void* d_out, int out_size, void* d_ws, size_t ws_size,
                              hipStream_t stream) {
    const float* x    = (const float*)d_in[0];
    const float* wg   = (const float*)d_in[1];
    const float* wexp = (const float*)d_in[2];
    const float* bexp = (const float*)d_in[3];
    // d_in[4] is k==4 (hard-coded in kernels)
    float* out = (float*)d_out;
    char*  ws  = (char*)d_ws;

    unsigned short* wT    = (unsigned short*)ws;        // 67108864 B
    unsigned short* xb    = (unsigned short*)(ws + 67108864);  // 8388608 B
    float*          gates = (float*)(ws + 75497472);    // 131072 B
    float*          stats = (float*)(ws + 75628544);    // 64 B

    zero_stats_kernel<<<1, 64, 0, stream>>>(stats);
    {
        dim3 tg(C_DIM / 64, D_DIM / 64, E_NUM);
        transpose_wexp_kernel<<<tg, 256, 0, stream>>>(wexp, wT);
    }
    cvt_x_kernel<<<(B_ROWS * D_DIM / 4) / 256, 256, 0, stream>>>((const float4*)x, xb);
    gating_kernel<<<B_ROWS / 64, 256, 0, stream>>>(x, wg, gates, stats);
    loss_kernel<<<1, 64, 0, stream>>>(stats, out + (size_t)B_ROWS * C_DIM);

    dim3 grid(B_ROWS / 128, C_DIM / 128);
    moe_main_kernel<<<grid, 256, 0, stream>>>(xb, wT, bexp, gates, out);
}

// Round 3
// 612.770 us; speedup vs baseline: 1.4800x; 1.1063x over previous
//
#include <hip/hip_runtime.h>
#include <stdint.h>

#define B_ROWS 4096
#define D_DIM  1024
#define E_NUM  8
#define C_DIM  4096
#define LOSS_COEF 0.01f
#define EPS_COMBINE 2.220446049250313e-16f

typedef float  f32x4  __attribute__((ext_vector_type(4)));
typedef __bf16 bf16x8 __attribute__((ext_vector_type(8)));

// RNE float -> bf16 bits (values here are tame; no NaN handling needed)
static __device__ __forceinline__ unsigned short f2bf(float f) {
    unsigned int u = __float_as_uint(f);
    u += 0x7fffu + ((u >> 16) & 1u);
    return (unsigned short)(u >> 16);
}

// async global->LDS, 16B per lane; LDS dest = wave-uniform base + lane*16
static __device__ __forceinline__ void async16(const void* g, void* l) {
    __builtin_amdgcn_global_load_lds(
        (const __attribute__((address_space(1))) unsigned int*)g,
        (__attribute__((address_space(3))) unsigned int*)l, 16, 0, 0);
}

__global__ void zero_stats_kernel(float* __restrict__ stats) {
    if (threadIdx.x < 16) stats[threadIdx.x] = 0.0f;
}

// w_exp [8][1024][4096] fp32  ->  wT [8][4096][1024] bf16 (k-contiguous)
// float4 global reads (1KB/wave/instr); pad-68 LDS; phase2 mapping is
// conflict-free (lane -> consecutive cl within a 16-lane phase).
__global__ __launch_bounds__(256) void transpose_wexp_kernel(
    const float* __restrict__ wexp, unsigned short* __restrict__ wT) {
    __shared__ float T[64][68];
    const int e  = blockIdx.z;
    const int k0 = blockIdx.y * 64;
    const int c0 = blockIdx.x * 64;
    const int t  = threadIdx.x;
    const float* src = wexp + ((size_t)e * D_DIM + k0) * C_DIM + c0;
    #pragma unroll
    for (int i = 0; i < 4; ++i) {
        int kr = i * 16 + (t >> 4);
        int cg = (t & 15) * 4;
        float4 v = *(const float4*)(src + (size_t)kr * C_DIM + cg);
        *(float4*)&T[kr][cg] = v;          // (kr*68+cg)%4==0 -> 16B aligned
    }
    __syncthreads();
    const int cl  = t & 63;                // local c
    const int k16 = (t >> 6) * 16;         // wave-uniform k chunk
    unsigned short h[16];
    #pragma unroll
    for (int j = 0; j < 16; ++j) h[j] = f2bf(T[k16 + j][cl]);
    unsigned short* dst = wT + ((size_t)(e * C_DIM + c0 + cl)) * D_DIM + k0 + k16;
    *(uint4*)dst       = ((const uint4*)h)[0];
    *(uint4*)(dst + 8) = ((const uint4*)h)[1];
}

// One wave per row: logits = x @ w_gate, top-4 softmax -> gates[4096][8],
// importance/load atomics. Also emits xb (bf16 x) from the rows it loads.
__global__ __launch_bounds__(256) void gating_kernel(
    const float* __restrict__ x,
    const float* __restrict__ wg,
    unsigned short* __restrict__ xb,
    float* __restrict__ gates,
    float* __restrict__ stats) {
    __shared__ float simp[E_NUM], sload[E_NUM];
    const int tid = threadIdx.x;
    if (tid < E_NUM) { simp[tid] = 0.0f; sload[tid] = 0.0f; }
    __syncthreads();
    const int lane = tid & 63;
    const int wid  = tid >> 6;
    const int row  = blockIdx.x * 4 + wid;

    float acc[8] = {0.f,0.f,0.f,0.f,0.f,0.f,0.f,0.f};
    #pragma unroll
    for (int i = 0; i < 4; ++i) {
        int d = i * 256 + lane * 4;
        float4 xv = *(const float4*)(x + (size_t)row * D_DIM + d);
        unsigned short hh[4] = { f2bf(xv.x), f2bf(xv.y), f2bf(xv.z), f2bf(xv.w) };
        *(uint2*)(xb + (size_t)row * D_DIM + d) = *(const uint2*)hh;
        float xa[4] = { xv.x, xv.y, xv.z, xv.w };
        #pragma unroll
        for (int j = 0; j < 4; ++j) {
            const float4* wp = (const float4*)(wg + (size_t)(d + j) * 8);
            float4 w0 = wp[0], w1 = wp[1];
            acc[0] += xa[j] * w0.x; acc[1] += xa[j] * w0.y;
            acc[2] += xa[j] * w0.z; acc[3] += xa[j] * w0.w;
            acc[4] += xa[j] * w1.x; acc[5] += xa[j] * w1.y;
            acc[6] += xa[j] * w1.z; acc[7] += xa[j] * w1.w;
        }
    }
    #pragma unroll
    for (int off = 32; off > 0; off >>= 1)
        #pragma unroll
        for (int e = 0; e < 8; ++e)
            acc[e] += __shfl_xor(acc[e], off, 64);
    if (lane == 0) {
        float val[4]; int idx[4]; unsigned used = 0;
        #pragma unroll
        for (int j = 0; j < 4; ++j) {           // strict > : lowest index wins ties
            float best = -1e30f; int bi = 0;
            for (int ee = 0; ee < 8; ++ee)
                if (!(used & (1u << ee)) && acc[ee] > best) { best = acc[ee]; bi = ee; }
            used |= 1u << bi; val[j] = best; idx[j] = bi;
        }
        float mx = val[0], sum = 0.f, gv[4];
        #pragma unroll
        for (int j = 0; j < 4; ++j) { gv[j] = __expf(val[j] - mx); sum += gv[j]; }
        float inv = 1.0f / sum;
        float gout[8] = {0.f,0.f,0.f,0.f,0.f,0.f,0.f,0.f};
        #pragma unroll
        for (int j = 0; j < 4; ++j) gout[idx[j]] = gv[j] * inv;
        #pragma unroll
        for (int e = 0; e < 8; ++e) gates[(size_t)row * 8 + e] = gout[e];
        #pragma unroll
        for (int j = 0; j < 4; ++j) {
            atomicAdd(&simp[idx[j]], gv[j] * inv);
            atomicAdd(&sload[idx[j]], 1.0f);
        }
    }
    __syncthreads();
    if (tid < E_NUM) {
        atomicAdd(&stats[tid],          simp[tid]);
        atomicAdd(&stats[E_NUM + tid],  sload[tid]);
    }
}

__global__ void loss_kernel(const float* __restrict__ stats, float* __restrict__ out_loss) {
    if (threadIdx.x == 0) {
        float mi = 0.f, ml = 0.f;
        for (int e = 0; e < 8; ++e) { mi += stats[e]; ml += stats[8 + e]; }
        mi *= 0.125f; ml *= 0.125f;
        float vi = 0.f, vl = 0.f;
        for (int e = 0; e < 8; ++e) {
            float a = stats[e] - mi;     vi += a * a;
            float b = stats[8 + e] - ml; vl += b * b;
        }
        vi *= (1.0f / 7.0f); vl *= (1.0f / 7.0f);
        out_loss[0] = (vi / (mi * mi + 1e-10f) + vl / (ml * ml + 1e-10f)) * LOSS_COEF;
    }
}

// Fused dense MoE, 128x128 tile, 512 threads = 8 waves of 64x32 each.
// Per expert: bf16 MFMA GEMM over K=1024, then comb += gate*exp(acc+bias);
// final y = log(comb). acc+comb = 64 f32 regs/thread -> <=128 total regs
// -> 16 waves/CU (vs 8 in the 4-wave variant): doubles barrier-drain hiding.
__global__ __launch_bounds__(512, 4) void moe_main_kernel(
    const unsigned short* __restrict__ xb,   // bf16 bits [4096][1024]
    const unsigned short* __restrict__ wT,   // bf16 bits [8][4096][1024]
    const float* __restrict__ bexp,          // [8][4096]
    const float* __restrict__ gates,         // [4096][8]
    float* __restrict__ out)                 // [4096][4096] (+ loss at end)
{
    __shared__ unsigned short As[128 * 32];  // [m][k-chunk swizzled], 8KB
    __shared__ unsigned short Bs[128 * 32];  // [n][k-chunk swizzled], 8KB
    __shared__ float gs[128 * 9];            // gates tile, pad 9 (bank spread)
    __shared__ float bs[8 * 128];            // bias tile

    const int tid  = threadIdx.x;
    const int lane = tid & 63;
    const int wid  = tid >> 6;     // 0..7
    const int wm   = wid >> 2;     // 2x4 wave grid, each wave 64 rows x 32 cols
    const int wn   = wid & 3;
    const int q    = lane >> 4;
    const int ln   = lane & 15;
    const int row0 = blockIdx.x * 128;
    const int col0 = blockIdx.y * 128;

    for (int i = tid; i < 1024; i += 512)
        gs[(i >> 3) * 9 + (i & 7)] = gates[(size_t)row0 * 8 + i];
    {
        int e = tid >> 6, c2 = (tid & 63) * 2;
        *(float2*)(bs + e * 128 + c2) = *(const float2*)(bexp + (size_t)e * C_DIM + col0 + c2);
    }

    const f32x4 vzero = {0.f, 0.f, 0.f, 0.f};
    f32x4 comb[4][2];
    #pragma unroll
    for (int i = 0; i < 4; ++i)
        #pragma unroll
        for (int j = 0; j < 2; ++j) comb[i][j] = vzero;

    // staging: thread t -> LDS slot (row = t>>2, qs = t&3), source chunk
    // qg = qs ^ (row&3) (XOR swizzle); fragment reads use chunk q^(ln&3).
    const int rS = tid >> 2;
    const int qg = (tid & 3) ^ (rS & 3);
    const unsigned short* gA  = xb + (size_t)(row0 + rS) * D_DIM + qg * 8;
    const unsigned short* gBb = wT + (size_t)(col0 + rS) * D_DIM + qg * 8;
    char* ldsA = (char*)As + wid * 1024;     // wave-uniform base; HW adds lane*16
    char* ldsB = (char*)Bs + wid * 1024;

    const int fq = ((q ^ (ln & 3)) << 3);    // swizzled fragment chunk (shorts)

    for (int e = 0; e < E_NUM; ++e) {
        f32x4 acc[4][2];
        #pragma unroll
        for (int i = 0; i < 4; ++i)
            #pragma unroll
            for (int j = 0; j < 2; ++j) acc[i][j] = vzero;

        const unsigned short* gB = gBb + (size_t)e * C_DIM * D_DIM;

        for (int kt = 0; kt < D_DIM / 32; ++kt) {
            async16(gA + kt * 32, ldsA);
            async16(gB + kt * 32, ldsB);

            __syncthreads();

            bf16x8 af[4], bfr[2];
            #pragma unroll
            for (int fm = 0; fm < 4; ++fm)
                af[fm] = *(const bf16x8*)(As + (wm * 64 + fm * 16 + ln) * 32 + fq);
            #pragma unroll
            for (int fn = 0; fn < 2; ++fn)
                bfr[fn] = *(const bf16x8*)(Bs + (wn * 32 + fn * 16 + ln) * 32 + fq);
            #pragma unroll
            for (int fm = 0; fm < 4; ++fm)
                #pragma unroll
                for (int fn = 0; fn < 2; ++fn)
                    acc[fm][fn] = __builtin_amdgcn_mfma_f32_16x16x32_bf16(
                        af[fm], bfr[fn], acc[fm][fn], 0, 0, 0);

            __syncthreads();
        }

        // epilogue: comb += gate * exp(acc + bias)   (C/D: col=ln, row=q*4+r)
        #pragma unroll
        for (int fn = 0; fn < 2; ++fn) {
            float bval = bs[e * 128 + wn * 32 + fn * 16 + ln];
            #pragma unroll
            for (int fm = 0; fm < 4; ++fm)
                #pragma unroll
                for (int r = 0; r < 4; ++r) {
                    float g = gs[(wm * 64 + fm * 16 + q * 4 + r) * 9 + e];
                    comb[fm][fn][r] += g * __expf(acc[fm][fn][r] + bval);
                }
        }
    }

    #pragma unroll
    for (int fm = 0; fm < 4; ++fm)
        #pragma unroll
        for (int fn = 0; fn < 2; ++fn)
            #pragma unroll
            for (int r = 0; r < 4; ++r) {
                int row = row0 + wm * 64 + fm * 16 + q * 4 + r;
                int col = col0 + wn * 32 + fn * 16 + ln;
                float c = comb[fm][fn][r];
                c = (c == 0.0f) ? EPS_COMBINE : c;
                out[(size_t)row * C_DIM + col] = __logf(c);
            }
}

extern "C" void kernel_launch(void* const* d_in, const int* in_sizes, int n_in,
                              void* d_out, int out_size, void* d_ws, size_t ws_size,
                              hipStream_t stream) {
    const float* x    = (const float*)d_in[0];
    const float* wg   = (const float*)d_in[1];
    const float* wexp = (const float*)d_in[2];
    const float* bexp = (const float*)d_in[3];
    // d_in[4] is k==4 (hard-coded in kernels)
    float* out = (float*)d_out;
    char*  ws  = (char*)d_ws;

    unsigned short* wT    = (unsigned short*)ws;               // 67108864 B
    unsigned short* xb    = (unsigned short*)(ws + 67108864);  // 8388608 B
    float*          gates = (float*)(ws + 75497472);           // 131072 B
    float*          stats = (float*)(ws + 75628544);           // 64 B

    zero_stats_kernel<<<1, 64, 0, stream>>>(stats);
    {
        dim3 tg(C_DIM / 64, D_DIM / 64, E_NUM);
        transpose_wexp_kernel<<<tg, 256, 0, stream>>>(wexp, wT);
    }
    gating_kernel<<<B_ROWS / 4, 256, 0, stream>>>(x, wg, xb, gates, stats);
    loss_kernel<<<1, 64, 0, stream>>>(stats, out + (size_t)B_ROWS * C_DIM);

    dim3 grid(B_ROWS / 128, C_DIM / 128);
    moe_main_kernel<<<grid, 512, 0, stream>>>(xb, wT, bexp, gates, out);
}

// Round 4
// 581.814 us; speedup vs baseline: 1.5587x; 1.0532x over previous
//
#include <hip/hip_runtime.h>
#include <stdint.h>

#define B_ROWS 4096
#define D_DIM  1024
#define E_NUM  8
#define C_DIM  4096
#define LOSS_COEF 0.01f
#define EPS_COMBINE 2.220446049250313e-16f

typedef float  f32x4  __attribute__((ext_vector_type(4)));
typedef __bf16 bf16x8 __attribute__((ext_vector_type(8)));

// RNE float -> bf16 bits (values here are tame; no NaN handling needed)
static __device__ __forceinline__ unsigned short f2bf(float f) {
    unsigned int u = __float_as_uint(f);
    u += 0x7fffu + ((u >> 16) & 1u);
    return (unsigned short)(u >> 16);
}

// async global->LDS, 16B per lane; LDS dest = wave-uniform base + lane*16
static __device__ __forceinline__ void async16(const void* g, void* l) {
    __builtin_amdgcn_global_load_lds(
        (const __attribute__((address_space(1))) unsigned int*)g,
        (__attribute__((address_space(3))) unsigned int*)l, 16, 0, 0);
}

__global__ void zero_stats_kernel(float* __restrict__ stats) {
    if (threadIdx.x < 16) stats[threadIdx.x] = 0.0f;
}

// w_exp [8][1024][4096] fp32 -> wT [8][4096][1024] bf16 (k-contiguous).
// 3-phase: fp32 LDS tile (coalesced reads) -> bf16 LDS tile (conflict-light
// writes) -> fully coalesced global writes (128B contiguous per 8 lanes).
__global__ __launch_bounds__(256) void transpose_wexp_kernel(
    const float* __restrict__ wexp, unsigned short* __restrict__ wT) {
    __shared__ float T[64][68];           // pad 68: conflict-free col reads
    __shared__ unsigned short W[64][72];  // pad 72: 16B-aligned, 2-way max
    const int e  = blockIdx.z;
    const int k0 = blockIdx.y * 64;
    const int c0 = blockIdx.x * 64;
    const int t  = threadIdx.x;
    const float* src = wexp + ((size_t)e * D_DIM + k0) * C_DIM + c0;
    #pragma unroll
    for (int i = 0; i < 4; ++i) {
        int kr = i * 16 + (t >> 4);
        int cg = (t & 15) * 4;
        *(float4*)&T[kr][cg] = *(const float4*)(src + (size_t)kr * C_DIM + cg);
    }
    __syncthreads();
    {
        const int c  = t & 63;
        const int kq = (t >> 6) * 16;
        unsigned short h[16];
        #pragma unroll
        for (int j = 0; j < 16; ++j) h[j] = f2bf(T[kq + j][c]);
        *(uint4*)&W[c][kq]     = ((const uint4*)h)[0];
        *(uint4*)&W[c][kq + 8] = ((const uint4*)h)[1];
    }
    __syncthreads();
    unsigned short* dstb = wT + (size_t)e * C_DIM * D_DIM;
    #pragma unroll
    for (int r = 0; r < 2; ++r) {
        int i  = r * 256 + t;
        int c3 = i >> 3;
        int k8 = (i & 7) * 8;
        *(uint4*)(dstb + (size_t)(c0 + c3) * D_DIM + k0 + k8) = *(const uint4*)&W[c3][k8];
    }
}

// One wave per row: logits = x @ w_gate, top-4 softmax -> gates[4096][8],
// importance/load atomics. Also emits xb (bf16 x) from the rows it loads.
__global__ __launch_bounds__(256) void gating_kernel(
    const float* __restrict__ x,
    const float* __restrict__ wg,
    unsigned short* __restrict__ xb,
    float* __restrict__ gates,
    float* __restrict__ stats) {
    __shared__ float simp[E_NUM], sload[E_NUM];
    const int tid = threadIdx.x;
    if (tid < E_NUM) { simp[tid] = 0.0f; sload[tid] = 0.0f; }
    __syncthreads();
    const int lane = tid & 63;
    const int wid  = tid >> 6;
    const int row  = blockIdx.x * 4 + wid;

    float acc[8] = {0.f,0.f,0.f,0.f,0.f,0.f,0.f,0.f};
    #pragma unroll
    for (int i = 0; i < 4; ++i) {
        int d = i * 256 + lane * 4;
        float4 xv = *(const float4*)(x + (size_t)row * D_DIM + d);
        unsigned short hh[4] = { f2bf(xv.x), f2bf(xv.y), f2bf(xv.z), f2bf(xv.w) };
        *(uint2*)(xb + (size_t)row * D_DIM + d) = *(const uint2*)hh;
        float xa[4] = { xv.x, xv.y, xv.z, xv.w };
        #pragma unroll
        for (int j = 0; j < 4; ++j) {
            const float4* wp = (const float4*)(wg + (size_t)(d + j) * 8);
            float4 w0 = wp[0], w1 = wp[1];
            acc[0] += xa[j] * w0.x; acc[1] += xa[j] * w0.y;
            acc[2] += xa[j] * w0.z; acc[3] += xa[j] * w0.w;
            acc[4] += xa[j] * w1.x; acc[5] += xa[j] * w1.y;
            acc[6] += xa[j] * w1.z; acc[7] += xa[j] * w1.w;
        }
    }
    #pragma unroll
    for (int off = 32; off > 0; off >>= 1)
        #pragma unroll
        for (int e = 0; e < 8; ++e)
            acc[e] += __shfl_xor(acc[e], off, 64);
    if (lane == 0) {
        float val[4]; int idx[4]; unsigned used = 0;
        #pragma unroll
        for (int j = 0; j < 4; ++j) {           // strict > : lowest index wins ties
            float best = -1e30f; int bi = 0;
            for (int ee = 0; ee < 8; ++ee)
                if (!(used & (1u << ee)) && acc[ee] > best) { best = acc[ee]; bi = ee; }
            used |= 1u << bi; val[j] = best; idx[j] = bi;
        }
        float mx = val[0], sum = 0.f, gv[4];
        #pragma unroll
        for (int j = 0; j < 4; ++j) { gv[j] = __expf(val[j] - mx); sum += gv[j]; }
        float inv = 1.0f / sum;
        float gout[8] = {0.f,0.f,0.f,0.f,0.f,0.f,0.f,0.f};
        #pragma unroll
        for (int j = 0; j < 4; ++j) gout[idx[j]] = gv[j] * inv;
        #pragma unroll
        for (int e = 0; e < 8; ++e) gates[(size_t)row * 8 + e] = gout[e];
        #pragma unroll
        for (int j = 0; j < 4; ++j) {
            atomicAdd(&simp[idx[j]], gv[j] * inv);
            atomicAdd(&sload[idx[j]], 1.0f);
        }
    }
    __syncthreads();
    if (tid < E_NUM) {
        atomicAdd(&stats[tid],          simp[tid]);
        atomicAdd(&stats[E_NUM + tid],  sload[tid]);
    }
}

__global__ void loss_kernel(const float* __restrict__ stats, float* __restrict__ out_loss) {
    if (threadIdx.x == 0) {
        float mi = 0.f, ml = 0.f;
        for (int e = 0; e < 8; ++e) { mi += stats[e]; ml += stats[8 + e]; }
        mi *= 0.125f; ml *= 0.125f;
        float vi = 0.f, vl = 0.f;
        for (int e = 0; e < 8; ++e) {
            float a = stats[e] - mi;     vi += a * a;
            float b = stats[8 + e] - ml; vl += b * b;
        }
        vi *= (1.0f / 7.0f); vl *= (1.0f / 7.0f);
        out_loss[0] = (vi / (mi * mi + 1e-10f) + vl / (ml * ml + 1e-10f)) * LOSS_COEF;
    }
}

// Fused dense MoE. Tile 128 rows x 64 cols, 256 thr = 4 waves (2x2), each
// wave 64x32 x 2 EXPERTS per pass (4 passes of the K loop). Processing 2
// experts per A-fragment read doubles effective patch area without growing
// comb: LDS reads 0.0305 B/FLOP (vs 0.0457 in the 1-expert 8-wave variant).
__global__ __launch_bounds__(256, 3) void moe_main_kernel(
    const unsigned short* __restrict__ xb,   // bf16 bits [4096][1024]
    const unsigned short* __restrict__ wT,   // bf16 bits [8][4096][1024]
    const float* __restrict__ bexp,          // [8][4096]
    const float* __restrict__ gates,         // [4096][8]
    float* __restrict__ out)                 // [4096][4096] (+ loss at end)
{
    __shared__ unsigned short As[128 * 32];      // [m][k-chunk swizzled], 8KB
    __shared__ unsigned short Bs[2 * 64 * 32];   // [e][n][k-chunk swizzled], 8KB
    __shared__ float gs[128 * 9];                // gates tile (pad 9)
    __shared__ float bs[8 * 64];                 // bias tile

    const int tid  = threadIdx.x;
    const int lane = tid & 63;
    const int wid  = tid >> 6;     // 0..3
    const int wm   = wid >> 1;     // 2x2 wave grid: 64 rows x 32 cols each
    const int wn   = wid & 1;
    const int q    = lane >> 4;
    const int ln   = lane & 15;
    const int row0 = blockIdx.x * 128;
    const int col0 = blockIdx.y * 64;

    #pragma unroll
    for (int i = 0; i < 4; ++i) {
        int idx = i * 256 + tid;
        gs[(idx >> 3) * 9 + (idx & 7)] = gates[(size_t)row0 * 8 + idx];
    }
    {
        int e = tid >> 5, c = tid & 31;
        bs[e * 64 + c]      = bexp[(size_t)e * C_DIM + col0 + c];
        bs[e * 64 + c + 32] = bexp[(size_t)e * C_DIM + col0 + c + 32];
    }

    const f32x4 vzero = {0.f, 0.f, 0.f, 0.f};
    f32x4 comb[4][2];
    #pragma unroll
    for (int i = 0; i < 4; ++i)
        #pragma unroll
        for (int j = 0; j < 2; ++j) comb[i][j] = vzero;

    // staging: thread t -> LDS slot (row = t>>2, qs = t&3), source chunk
    // qg = qs ^ (row&3) (XOR swizzle); fragment reads use chunk q^(ln&3).
    const int rS = tid >> 2;                 // A row 0..63(+64) / B col 0..63
    const int qg = (tid & 3) ^ (rS & 3);
    const unsigned short* gA  = xb + (size_t)(row0 + rS) * D_DIM + qg * 8;
    const unsigned short* gBb = wT + (size_t)(col0 + rS) * D_DIM + qg * 8;
    char* ldsA = (char*)As + wid * 1024;     // wave-uniform base; HW adds lane*16
    char* ldsB = (char*)Bs + wid * 1024;

    const int fq = ((q ^ (ln & 3)) << 3);    // swizzled fragment chunk (shorts)

    for (int eg = 0; eg < 4; ++eg) {
        f32x4 acc[4][2][2];                  // [fm][fn][expert]
        #pragma unroll
        for (int i = 0; i < 4; ++i)
            #pragma unroll
            for (int j = 0; j < 2; ++j)
                #pragma unroll
                for (int e = 0; e < 2; ++e) acc[i][j][e] = vzero;

        const unsigned short* gB0 = gBb + (size_t)(2 * eg)     * C_DIM * D_DIM;
        const unsigned short* gB1 = gBb + (size_t)(2 * eg + 1) * C_DIM * D_DIM;

        for (int kt = 0; kt < D_DIM / 32; ++kt) {
            const int ko = kt * 32;
            async16(gA + ko,               ldsA);          // A rows 0-63
            async16(gA + ko + 64 * D_DIM,  ldsA + 4096);   // A rows 64-127
            async16(gB0 + ko,              ldsB);          // B expert 0
            async16(gB1 + ko,              ldsB + 4096);   // B expert 1

            __syncthreads();

            bf16x8 af[4], bfr[2][2];
            #pragma unroll
            for (int fm = 0; fm < 4; ++fm)
                af[fm] = *(const bf16x8*)(As + (wm * 64 + fm * 16 + ln) * 32 + fq);
            #pragma unroll
            for (int fn = 0; fn < 2; ++fn)
                #pragma unroll
                for (int e = 0; e < 2; ++e)
                    bfr[fn][e] = *(const bf16x8*)(Bs + e * 2048 +
                                    (wn * 32 + fn * 16 + ln) * 32 + fq);
            #pragma unroll
            for (int fm = 0; fm < 4; ++fm)
                #pragma unroll
                for (int fn = 0; fn < 2; ++fn)
                    #pragma unroll
                    for (int e = 0; e < 2; ++e)
                        acc[fm][fn][e] = __builtin_amdgcn_mfma_f32_16x16x32_bf16(
                            af[fm], bfr[fn][e], acc[fm][fn][e], 0, 0, 0);

            __syncthreads();
        }

        // epilogue: comb += gate * exp(acc + bias)   (C/D: col=ln, row=q*4+r)
        #pragma unroll
        for (int e = 0; e < 2; ++e) {
            int eG = eg * 2 + e;
            #pragma unroll
            for (int fn = 0; fn < 2; ++fn) {
                float bval = bs[eG * 64 + wn * 32 + fn * 16 + ln];
                #pragma unroll
                for (int fm = 0; fm < 4; ++fm)
                    #pragma unroll
                    for (int r = 0; r < 4; ++r) {
                        float g = gs[(wm * 64 + fm * 16 + q * 4 + r) * 9 + eG];
                        comb[fm][fn][r] += g * __expf(acc[fm][fn][e][r] + bval);
                    }
            }
        }
    }

    #pragma unroll
    for (int fm = 0; fm < 4; ++fm)
        #pragma unroll
        for (int fn = 0; fn < 2; ++fn)
            #pragma unroll
            for (int r = 0; r < 4; ++r) {
                int row = row0 + wm * 64 + fm * 16 + q * 4 + r;
                int col = col0 + wn * 32 + fn * 16 + ln;
                float c = comb[fm][fn][r];
                c = (c == 0.0f) ? EPS_COMBINE : c;
                out[(size_t)row * C_DIM + col] = __logf(c);
            }
}

extern "C" void kernel_launch(void* const* d_in, const int* in_sizes, int n_in,
                              void* d_out, int out_size, void* d_ws, size_t ws_size,
                              hipStream_t stream) {
    const float* x    = (const float*)d_in[0];
    const float* wg   = (const float*)d_in[1];
    const float* wexp = (const float*)d_in[2];
    const float* bexp = (const float*)d_in[3];
    // d_in[4] is k==4 (hard-coded in kernels)
    float* out = (float*)d_out;
    char*  ws  = (char*)d_ws;

    unsigned short* wT    = (unsigned short*)ws;               // 67108864 B
    unsigned short* xb    = (unsigned short*)(ws + 67108864);  // 8388608 B
    float*          gates = (float*)(ws + 75497472);           // 131072 B
    float*          stats = (float*)(ws + 75628544);           // 64 B

    zero_stats_kernel<<<1, 64, 0, stream>>>(stats);
    {
        dim3 tg(C_DIM / 64, D_DIM / 64, E_NUM);
        transpose_wexp_kernel<<<tg, 256, 0, stream>>>(wexp, wT);
    }
    gating_kernel<<<B_ROWS / 4, 256, 0, stream>>>(x, wg, xb, gates, stats);
    loss_kernel<<<1, 64, 0, stream>>>(stats, out + (size_t)B_ROWS * C_DIM);

    dim3 grid(B_ROWS / 128, C_DIM / 64);
    moe_main_kernel<<<grid, 256, 0, stream>>>(xb, wT, bexp, gates, out);
}